// Round 3
// baseline (1367.395 us; speedup 1.0000x reference)
//
#include <hip/hip_runtime.h>
#include <hip/hip_bf16.h>

typedef __hip_bfloat16 bf16;
typedef __attribute__((ext_vector_type(8))) short s16x8;   // 8 bf16 (4 VGPRs) MFMA frag
typedef __attribute__((ext_vector_type(4))) float f32x4;   // MFMA accumulator

#define NN 1024      // nodes
#define NE 30720     // edges
#define EC 7680      // fc2+TP edge chunk (4 chunks)
#define CS 32
#define CV 8
#define CZ 128
#define INS 28
#define INV 37
#define NRDIM 139    // 28 + 3*37
#define INZ 1664
#define WN 1664      // WEIGHT_NUMEL
#define NL 4

__device__ __forceinline__ float b2f(bf16 x) { return __bfloat162float(x); }
__device__ __forceinline__ bf16 f2b(float x) { return __float2bfloat16(x); }

// ---------------------------------------------------------------------------
// Generic MFMA GEMM:  C[M,N] = act(A[M,K] @ Bt[N,K]^T + bias[N])
// A: bf16 row-major (AF32=0) or fp32 row-major (AF32=1, converted in staging).
// Bt bf16 row-major [N,K]. bias fp32. M%128==0, N%128==0, K%32==0 everywhere.
// 128x128 tile, BK=32, 4 waves each 64x64 (4x4 tiles of 16x16x32 MFMA).
// LDS stride 40 bf16 (=80B) breaks power-of-2 bank aliasing.
// ---------------------------------------------------------------------------
template<int RELU, int OUTBF, int AF32>
__global__ __launch_bounds__(256)
void gemm_bt(const void* __restrict__ Ap, const bf16* __restrict__ Bt,
             const float* __restrict__ bias, void* __restrict__ Cp,
             int M, int N, int K)
{
    __shared__ __align__(16) bf16 la[128 * 40];
    __shared__ __align__(16) bf16 lb[128 * 40];
    const int bm = blockIdx.x * 128;
    const int bn = blockIdx.y * 128;
    const int tid = threadIdx.x;
    const int lane = tid & 63;
    const int wv = tid >> 6;
    const int wm = (wv >> 1) * 64;
    const int wn = (wv & 1) * 64;
    const int lr = tid >> 1;          // loader row 0..127
    const int lc = (tid & 1) * 16;    // loader col 0 or 16
    const int l15 = lane & 15;
    const int quad = lane >> 4;
    f32x4 acc[4][4] = {};
    const bf16*  ga16 = (const bf16*) Ap + (size_t)(bm + lr) * K + lc;
    const float* ga32 = (const float*)Ap + (size_t)(bm + lr) * K + lc;
    const bf16*  gb   = Bt + (size_t)(bn + lr) * K + lc;
    for (int k0 = 0; k0 < K; k0 += 32) {
        union { bf16 h[16]; float4 q[2]; } pa;
        if (AF32) {
            float4 f0 = *(const float4*)(ga32 + k0);
            float4 f1 = *(const float4*)(ga32 + k0 + 4);
            float4 f2 = *(const float4*)(ga32 + k0 + 8);
            float4 f3 = *(const float4*)(ga32 + k0 + 12);
            pa.h[0]=f2b(f0.x); pa.h[1]=f2b(f0.y); pa.h[2]=f2b(f0.z); pa.h[3]=f2b(f0.w);
            pa.h[4]=f2b(f1.x); pa.h[5]=f2b(f1.y); pa.h[6]=f2b(f1.z); pa.h[7]=f2b(f1.w);
            pa.h[8]=f2b(f2.x); pa.h[9]=f2b(f2.y); pa.h[10]=f2b(f2.z); pa.h[11]=f2b(f2.w);
            pa.h[12]=f2b(f3.x); pa.h[13]=f2b(f3.y); pa.h[14]=f2b(f3.z); pa.h[15]=f2b(f3.w);
        } else {
            pa.q[0] = *(const float4*)(ga16 + k0);
            pa.q[1] = *(const float4*)(ga16 + k0 + 8);
        }
        float4 b0 = *(const float4*)(gb + k0);
        float4 b1 = *(const float4*)(gb + k0 + 8);
        __syncthreads();   // previous iteration's LDS reads done
        *(float4*)&la[lr * 40 + lc]     = pa.q[0];
        *(float4*)&la[lr * 40 + lc + 8] = pa.q[1];
        *(float4*)&lb[lr * 40 + lc]     = b0;
        *(float4*)&lb[lr * 40 + lc + 8] = b1;
        __syncthreads();
        s16x8 af[4], bf8[4];
#pragma unroll
        for (int i = 0; i < 4; i++)
            af[i] = *(const s16x8*)&la[(wm + i * 16 + l15) * 40 + quad * 8];
#pragma unroll
        for (int i = 0; i < 4; i++)
            bf8[i] = *(const s16x8*)&lb[(wn + i * 16 + l15) * 40 + quad * 8];
#pragma unroll
        for (int mi = 0; mi < 4; mi++)
#pragma unroll
            for (int ni = 0; ni < 4; ni++)
                acc[mi][ni] = __builtin_amdgcn_mfma_f32_16x16x32_bf16(af[mi], bf8[ni], acc[mi][ni], 0, 0, 0);
    }
    // epilogue: C/D layout col=lane&15, row=quad*4+reg  [m89/m91 verified]
#pragma unroll
    for (int ni = 0; ni < 4; ni++) {
        const int col = bn + wn + ni * 16 + l15;
        const float bv = bias[col];
#pragma unroll
        for (int mi = 0; mi < 4; mi++) {
            const int row0 = bm + wm + mi * 16 + quad * 4;
#pragma unroll
            for (int r = 0; r < 4; r++) {
                float v = acc[mi][ni][r] + bv;
                if (RELU) v = fmaxf(v, 0.f);
                if (OUTBF) ((bf16*)Cp)[(size_t)(row0 + r) * N + col] = f2b(v);
                else       ((float*)Cp)[(size_t)(row0 + r) * N + col] = v;
            }
        }
    }
}

// ---------------------------------------------------------------------------
// Weight convert+transpose: src fp32 [L,R,C] -> dst bf16 [L,C,R]
// ---------------------------------------------------------------------------
__global__ void transpose_b(const float* __restrict__ src, bf16* __restrict__ dst,
                            int L, int R, int C)
{
    int idx = blockIdx.x * 256 + threadIdx.x;
    if (idx >= L * R * C) return;
    int l = idx / (R * C);
    int rem = idx - l * R * C;
    int r = rem / C;
    int c = rem - r * C;
    dst[(size_t)l * R * C + (size_t)c * R + r] = f2b(src[idx]);
}

// ---------------------------------------------------------------------------
// Node embedding: xs[n,32] = node_raw[n,:28] @ ne_ws ; xv[n,8,3] from ne_wv
// ---------------------------------------------------------------------------
__global__ __launch_bounds__(64)
void node_embed(const float* __restrict__ node_raw, const float* __restrict__ ne_ws,
                const float* __restrict__ ne_wv, float* __restrict__ xs, float* __restrict__ xv)
{
    int n = blockIdx.x, t = threadIdx.x;
    const float* nr = node_raw + (size_t)n * NRDIM;
    if (t < 32) {
        float acc = 0.f;
        for (int i = 0; i < INS; i++) acc += nr[i] * ne_ws[i * CS + t];
        xs[n * CS + t] = acc;
    } else if (t < 56) {
        int t2 = t - 32, j = t2 / 3, x = t2 - 3 * (t2 / 3);
        float acc = 0.f;
        for (int i = 0; i < INV; i++) acc += nr[INS + i * 3 + x] * ne_wv[i * CV + j];
        xv[n * 24 + t2] = acc;
    }
}

__global__ void count_src(const int* __restrict__ ei, int* __restrict__ cnt)
{
    int e = blockIdx.x * 256 + threadIdx.x;
    if (e < NE) atomicAdd(&cnt[ei[NE + e]], 1);
}

__global__ void make_icnt(const int* __restrict__ cnt, float* __restrict__ icnt)
{
    int n = blockIdx.x * 256 + threadIdx.x;
    if (n < NN) icnt[n] = 1.0f / (float)(cnt[n] > 1 ? cnt[n] : 1);
}

// ---------------------------------------------------------------------------
// LayerNorm over 128 dims, bf16 input; optional bf16 residual (may alias out).
// ---------------------------------------------------------------------------
template<int RESID>
__global__ __launch_bounds__(128)
void ln_kernel(const bf16* __restrict__ xin, const bf16* resid,
               const float* __restrict__ g, const float* __restrict__ b,
               bf16* efb)
{
    __shared__ float red[4];
    int r = blockIdx.x, t = threadIdx.x;
    float x = b2f(xin[(size_t)r * CZ + t]);
    if (RESID) x += b2f(resid[(size_t)r * CZ + t]);
    float s = x, s2 = x * x;
    for (int o = 32; o > 0; o >>= 1) { s += __shfl_down(s, o); s2 += __shfl_down(s2, o); }
    int w = t >> 6;
    if ((t & 63) == 0) { red[w * 2] = s; red[w * 2 + 1] = s2; }
    __syncthreads();
    float mean = (red[0] + red[2]) * (1.f / 128.f);
    float var  = (red[1] + red[3]) * (1.f / 128.f) - mean * mean;
    float rstd = rsqrtf(var + 1e-5f);
    float y = (x - mean) * rstd * g[t] + b[t];
    efb[(size_t)r * CZ + t] = f2b(y);
}

// ---------------------------------------------------------------------------
// Tensor product + scatter for edges [e0, e0+EC). w is the CHUNK base.
// One wave per edge; messages pre-scaled by 1/cnt[src], atomic accumulate.
// ---------------------------------------------------------------------------
__global__ __launch_bounds__(256)
void tp_scatter(const bf16* __restrict__ w, int e0, const int* __restrict__ ei,
                const float* __restrict__ edge_vecs,
                const float* __restrict__ xs, const float* __restrict__ xv,
                const float* __restrict__ icnt,
                float* __restrict__ ags, float* __restrict__ agv)
{
    __shared__ float s_xs[4][32];
    __shared__ float s_xv[4][24];
    __shared__ float s_cr[4][24];
    __shared__ float s_y4[4][8];
    int wv = threadIdx.x >> 6;
    int lane = threadIdx.x & 63;
    int el = blockIdx.x * 4 + wv;       // local edge in chunk
    int e  = e0 + el;                   // global edge
    int dst = ei[e];
    int src = ei[NE + e];
    float vx = edge_vecs[e * 3 + 0];
    float vy = edge_vecs[e * 3 + 1];
    float vz = edge_vecs[e * 3 + 2];
    float sc = 1.7320508075688772f / (sqrtf(vx * vx + vy * vy + vz * vz) + 1e-8f);
    float shv[3] = { vx * sc, vy * sc, vz * sc };
    if (lane < 32)       s_xs[wv][lane] = xs[dst * CS + lane];
    else if (lane < 56)  s_xv[wv][lane - 32] = xv[dst * 24 + (lane - 32)];
    __syncthreads();
    if (lane >= 56) {
        int i = lane - 56;
        float x0 = s_xv[wv][i * 3 + 0], x1 = s_xv[wv][i * 3 + 1], x2 = s_xv[wv][i * 3 + 2];
        s_y4[wv][i] = x0 * shv[0] + x1 * shv[1] + x2 * shv[2];
        s_cr[wv][i * 3 + 0] = x1 * shv[2] - x2 * shv[1];
        s_cr[wv][i * 3 + 1] = x2 * shv[0] - x0 * shv[2];
        s_cr[wv][i * 3 + 2] = x0 * shv[1] - x1 * shv[0];
    }
    __syncthreads();
    const bf16* we = w + (size_t)el * WN;
    float ic = icnt[src];
    // path norms: a1=1/sqrt(64), a4/sqrt3, a2=1/sqrt(96), a3=1/sqrt(24), a5/sqrt2
    if (lane < 32) {
        int j = lane;
        float acc1 = 0.f, acc4 = 0.f;
        for (int i = 0; i < 32; i++) acc1 += s_xs[wv][i] * b2f(we[i * 32 + j]);
        for (int i = 0; i < 8; i++)  acc4 += s_y4[wv][i] * b2f(we[1344 + i * 32 + j]);
        float out = 0.125f * acc1 + 0.14433756729740643f * acc4;
        atomicAdd(&ags[src * CS + j], out * ic);
    } else if (lane < 56) {
        int t = lane - 32;
        int x = t >> 3, j = t & 7;
        float acc2 = 0.f, acc3 = 0.f, acc5 = 0.f;
        for (int i = 0; i < 32; i++) acc2 += s_xs[wv][i] * b2f(we[1024 + i * 8 + j]);
        for (int i = 0; i < 8; i++) {
            acc3 += s_xv[wv][i * 3 + x] * b2f(we[1280 + i * 8 + j]);
            acc5 += s_cr[wv][i * 3 + x] * b2f(we[1600 + i * 8 + j]);
        }
        float out = 0.10206207261596575f * shv[x] * acc2
                  + 0.2041241452319315f * acc3
                  + 0.14433756729740643f * acc5;
        atomicAdd(&agv[src * 24 + j * 3 + x], out * ic);
    }
}

__global__ void add_agg(float* __restrict__ xs, float* __restrict__ xv,
                        const float* __restrict__ ags, const float* __restrict__ agv)
{
    int idx = blockIdx.x * 256 + threadIdx.x;
    if (idx >= NN * 56) return;
    int n = idx / 56, d = idx - 56 * (idx / 56);
    if (d < 32) xs[n * CS + d] += ags[n * CS + d];
    else        xv[n * 24 + d - 32] += agv[n * 24 + d - 32];
}

// blocks 0..31: xs channel mean/rstd -> stats[0..63]; 32..39: xv scale -> stats[64..71]
__global__ __launch_bounds__(256)
void bn_stats(const float* __restrict__ xs, const float* __restrict__ xv,
              const float* __restrict__ bn_vg_l, float* __restrict__ stats)
{
    __shared__ float red[8];
    int c = blockIdx.x, t = threadIdx.x;
    if (c < 32) {
        float s = 0.f, s2 = 0.f;
        for (int n = t; n < NN; n += 256) { float v = xs[n * CS + c]; s += v; s2 += v * v; }
        for (int o = 32; o > 0; o >>= 1) { s += __shfl_down(s, o); s2 += __shfl_down(s2, o); }
        int w = t >> 6;
        if ((t & 63) == 0) { red[w * 2] = s; red[w * 2 + 1] = s2; }
        __syncthreads();
        if (t == 0) {
            float S = red[0] + red[2] + red[4] + red[6];
            float S2 = red[1] + red[3] + red[5] + red[7];
            float mean = S * (1.f / NN);
            float var = S2 * (1.f / NN) - mean * mean;
            stats[c] = mean;
            stats[32 + c] = rsqrtf(var + 1e-5f);
        }
    } else {
        int c2 = c - 32;
        float s = 0.f;
        for (int n = t; n < NN; n += 256) {
            float v0 = xv[n * 24 + c2 * 3 + 0];
            float v1 = xv[n * 24 + c2 * 3 + 1];
            float v2 = xv[n * 24 + c2 * 3 + 2];
            s += v0 * v0 + v1 * v1 + v2 * v2;
        }
        for (int o = 32; o > 0; o >>= 1) s += __shfl_down(s, o);
        int w = t >> 6;
        if ((t & 63) == 0) red[w] = s;
        __syncthreads();
        if (t == 0) {
            float fn = (red[0] + red[1] + red[2] + red[3]) * (1.f / (3.f * NN));
            stats[64 + c2] = bn_vg_l[c2] * rsqrtf(fn + 1e-5f);
        }
    }
}

__global__ void bn_apply(float* __restrict__ xs, float* __restrict__ xv,
                         const float* __restrict__ stats,
                         const float* __restrict__ g, const float* __restrict__ b)
{
    int idx = blockIdx.x * 256 + threadIdx.x;
    if (idx >= NN * 56) return;
    int n = idx / 56, d = idx - 56 * (idx / 56);
    if (d < 32) {
        float v = xs[n * CS + d];
        xs[n * CS + d] = (v - stats[d]) * stats[32 + d] * g[d] + b[d];
    } else {
        int t2 = d - 32, c = t2 / 3;
        xv[n * 24 + t2] *= stats[64 + c];
    }
}

// a[n,128] = xs[n,:] @ eu_lin[l]
__global__ __launch_bounds__(128)
void lin_a(const float* __restrict__ xs, const float* __restrict__ eu_lin_l,
           bf16* __restrict__ a_b)
{
    __shared__ float sxs[32];
    int n = blockIdx.x, t = threadIdx.x;
    if (t < 32) sxs[t] = xs[n * CS + t];
    __syncthreads();
    float acc = 0.f;
    for (int c = 0; c < 32; c++) acc += sxs[c] * eu_lin_l[c * CZ + t];
    a_b[(size_t)n * CZ + t] = f2b(acc);
}

// e_in[e, 0:128]=a[dst], [128:256]=a[src], [256:384]=ef
__global__ void build_ein(const bf16* __restrict__ a_b, const bf16* __restrict__ efb,
                          const int* __restrict__ ei, bf16* __restrict__ e_in)
{
    int idx = blockIdx.x * 256 + threadIdx.x;
    if (idx >= NE * 384) return;
    int e = idx / 384, d = idx - 384 * (idx / 384);
    bf16 v;
    if (d < 128)      v = a_b[(size_t)ei[e] * CZ + d];
    else if (d < 256) v = a_b[(size_t)ei[NE + e] * CZ + d - 128];
    else              v = efb[(size_t)e * CZ + d - 256];
    e_in[idx] = v;
}

// Final: xv_loc = R^T v per node, feat=[xs|xv_loc] (56), mu/lv heads -> out [2,N,128] fp32
__global__ __launch_bounds__(128)
void final_out(const float* __restrict__ xs, const float* __restrict__ xv,
               const float* __restrict__ rot,
               const float* __restrict__ mu_w, const float* __restrict__ mu_b,
               const float* __restrict__ lv_w, const float* __restrict__ lv_b,
               float* __restrict__ out)
{
    __shared__ float feat[56];
    int n = blockIdx.x, t = threadIdx.x;
    if (t < 32) feat[t] = xs[n * CS + t];
    else if (t < 56) {
        int t2 = t - 32, c = t2 / 3, y = t2 - 3 * (t2 / 3);
        float acc = 0.f;
        for (int x = 0; x < 3; x++)
            acc += rot[n * 9 + x * 3 + y] * xv[n * 24 + c * 3 + x];
        feat[t] = acc;
    }
    __syncthreads();
    float mu = mu_b[t], lv = lv_b[t];
    for (int d = 0; d < 56; d++) {
        float f = feat[d];
        mu += f * mu_w[d * 128 + t];
        lv += f * lv_w[d * 128 + t];
    }
    out[(size_t)n * 128 + t] = mu;
    out[(size_t)NN * 128 + (size_t)n * 128 + t] = lv;
}

// ---------------------------------------------------------------------------
extern "C" void kernel_launch(void* const* d_in, const int* in_sizes, int n_in,
                              void* d_out, int out_size, void* d_ws, size_t ws_size,
                              hipStream_t stream)
{
    (void)in_sizes; (void)n_in; (void)out_size; (void)ws_size;
    const float* node_raw  = (const float*)d_in[0];
    const float* edge_raw  = (const float*)d_in[1];
    const float* edge_vecs = (const float*)d_in[2];
    const float* rot       = (const float*)d_in[3];
    const int*   ei        = (const int*  )d_in[4];
    const float* ee_w1 = (const float*)d_in[5];
    const float* ee_b1 = (const float*)d_in[6];
    const float* ee_w2 = (const float*)d_in[7];
    const float* ee_b2 = (const float*)d_in[8];
    const float* ee_w3 = (const float*)d_in[9];
    const float* ee_b3 = (const float*)d_in[10];
    const float* ee_ln_g = (const float*)d_in[11];
    const float* ee_ln_b = (const float*)d_in[12];
    const float* ne_ws = (const float*)d_in[13];
    const float* ne_wv = (const float*)d_in[14];
    const float* fc_w1 = (const float*)d_in[15];
    const float* fc_b1 = (const float*)d_in[16];
    const float* fc_w2 = (const float*)d_in[17];
    const float* fc_b2 = (const float*)d_in[18];
    const float* bn_g  = (const float*)d_in[19];
    const float* bn_b  = (const float*)d_in[20];
    const float* bn_vg = (const float*)d_in[21];
    const float* eu_lin = (const float*)d_in[22];
    const float* eu_w1 = (const float*)d_in[23];
    const float* eu_b1 = (const float*)d_in[24];
    const float* eu_w2 = (const float*)d_in[25];
    const float* eu_b2 = (const float*)d_in[26];
    const float* eu_w3 = (const float*)d_in[27];
    const float* eu_b3 = (const float*)d_in[28];
    const float* eu_ln_g = (const float*)d_in[29];
    const float* eu_ln_b = (const float*)d_in[30];
    const float* mu_w = (const float*)d_in[31];
    const float* mu_b = (const float*)d_in[32];
    const float* lv_w = (const float*)d_in[33];
    const float* lv_b = (const float*)d_in[34];

    char* ws = (char*)d_ws;
    size_t off = 0;
    auto alloc = [&](size_t bytes) -> void* {
        void* p = ws + off;
        off += (bytes + 255) & ~(size_t)255;
        return p;
    };
    // total footprint ~53 MB
    bf16*  ef_b  = (bf16*) alloc((size_t)NE * CZ * 2);     //  7.86 MB (residual stream)
    bf16*  buf_a = (bf16*) alloc((size_t)NE * CZ * 2);     //  7.86 MB
    bf16*  buf_b = (bf16*) alloc((size_t)NE * CZ * 2);     //  7.86 MB
    bf16*  region= (bf16*) alloc((size_t)EC * WN * 2);     // 25.56 MB: w_chunk / e_in (time-disjoint)
    bf16*  w_chunk = region;                               // [EC, 1664]
    bf16*  e_in    = region;                               // [NE, 384] = 23.6 MB <= region
    float* xs    = (float*)alloc((size_t)NN * CS * 4);
    float* xv    = (float*)alloc((size_t)NN * 24 * 4);
    float* ags   = (float*)alloc((size_t)NN * CS * 4);
    float* agv   = (float*)alloc((size_t)NN * 24 * 4);
    int*   cnti  = (int*)  alloc((size_t)NN * 4);
    float* icnt  = (float*)alloc((size_t)NN * 4);
    float* stats = (float*)alloc(256 * 4);
    bf16*  a_b   = (bf16*) alloc((size_t)NN * CZ * 2);
    bf16* ee_w1t = (bf16*)alloc((size_t)INZ * CZ * 2);
    bf16* ee_w2t = (bf16*)alloc((size_t)CZ * CZ * 2);
    bf16* ee_w3t = (bf16*)alloc((size_t)CZ * CZ * 2);
    bf16* fc_w1t = (bf16*)alloc((size_t)NL * CZ * CZ * 2);
    bf16* fc_w2t = (bf16*)alloc((size_t)NL * WN * CZ * 2);
    bf16* eu_w1t = (bf16*)alloc((size_t)NL * 384 * CZ * 2);
    bf16* eu_w2t = (bf16*)alloc((size_t)NL * CZ * CZ * 2);
    bf16* eu_w3t = (bf16*)alloc((size_t)NL * CZ * CZ * 2);

    auto tg = [](int n) { return (n + 255) / 256; };
    transpose_b<<<tg(INZ * CZ), 256, 0, stream>>>(ee_w1, ee_w1t, 1, INZ, CZ);
    transpose_b<<<tg(CZ * CZ), 256, 0, stream>>>(ee_w2, ee_w2t, 1, CZ, CZ);
    transpose_b<<<tg(CZ * CZ), 256, 0, stream>>>(ee_w3, ee_w3t, 1, CZ, CZ);
    transpose_b<<<tg(NL * CZ * CZ), 256, 0, stream>>>(fc_w1, fc_w1t, NL, CZ, CZ);
    transpose_b<<<tg(NL * CZ * WN), 256, 0, stream>>>(fc_w2, fc_w2t, NL, CZ, WN);
    transpose_b<<<tg(NL * 384 * CZ), 256, 0, stream>>>(eu_w1, eu_w1t, NL, 384, CZ);
    transpose_b<<<tg(NL * CZ * CZ), 256, 0, stream>>>(eu_w2, eu_w2t, NL, CZ, CZ);
    transpose_b<<<tg(NL * CZ * CZ), 256, 0, stream>>>(eu_w3, eu_w3t, NL, CZ, CZ);

    node_embed<<<NN, 64, 0, stream>>>(node_raw, ne_ws, ne_wv, xs, xv);
    hipMemsetAsync(cnti, 0, NN * 4, stream);
    count_src<<<NE / 256, 256, 0, stream>>>(ei, cnti);
    make_icnt<<<NN / 256, 256, 0, stream>>>(cnti, icnt);

    // edge embedding MLP + LN  (edge_raw(fp32) -> buf_a -> buf_b -> buf_a -> ef_b)
    gemm_bt<1, 1, 1><<<dim3(NE / 128, 1), 256, 0, stream>>>(edge_raw, ee_w1t, ee_b1, buf_a, NE, CZ, INZ);
    gemm_bt<1, 1, 0><<<dim3(NE / 128, 1), 256, 0, stream>>>(buf_a, ee_w2t, ee_b2, buf_b, NE, CZ, CZ);
    gemm_bt<0, 1, 0><<<dim3(NE / 128, 1), 256, 0, stream>>>(buf_b, ee_w3t, ee_b3, buf_a, NE, CZ, CZ);
    ln_kernel<0><<<NE, 128, 0, stream>>>(buf_a, nullptr, ee_ln_g, ee_ln_b, ef_b);

    for (int l = 0; l < NL; l++) {
        gemm_bt<1, 1, 0><<<dim3(NE / 128, 1), 256, 0, stream>>>(
            ef_b, fc_w1t + (size_t)l * CZ * CZ, fc_b1 + l * CZ, buf_a, NE, CZ, CZ);
        hipMemsetAsync(ags, 0, NN * CS * 4, stream);
        hipMemsetAsync(agv, 0, NN * 24 * 4, stream);
        for (int c0 = 0; c0 < NE; c0 += EC) {
            gemm_bt<0, 1, 0><<<dim3(EC / 128, WN / 128), 256, 0, stream>>>(
                buf_a + (size_t)c0 * CZ, fc_w2t + (size_t)l * WN * CZ, fc_b2 + l * WN,
                w_chunk, EC, WN, CZ);
            tp_scatter<<<EC / 4, 256, 0, stream>>>(w_chunk, c0, ei, edge_vecs, xs, xv, icnt, ags, agv);
        }
        add_agg<<<(NN * 56) / 256, 256, 0, stream>>>(xs, xv, ags, agv);
        bn_stats<<<40, 256, 0, stream>>>(xs, xv, bn_vg + l * CV, stats);
        bn_apply<<<(NN * 56) / 256, 256, 0, stream>>>(xs, xv, stats, bn_g + l * CS, bn_b + l * CS);
        lin_a<<<NN, 128, 0, stream>>>(xs, eu_lin + (size_t)l * CS * CZ, a_b);
        build_ein<<<(NE * 384) / 256, 256, 0, stream>>>(a_b, ef_b, ei, e_in);
        gemm_bt<1, 1, 0><<<dim3(NE / 128, 1), 256, 0, stream>>>(
            e_in, eu_w1t + (size_t)l * 384 * CZ, eu_b1 + l * CZ, buf_a, NE, CZ, 384);
        gemm_bt<1, 1, 0><<<dim3(NE / 128, 1), 256, 0, stream>>>(
            buf_a, eu_w2t + (size_t)l * CZ * CZ, eu_b2 + l * CZ, buf_b, NE, CZ, CZ);
        gemm_bt<0, 1, 0><<<dim3(NE / 128, 1), 256, 0, stream>>>(
            buf_b, eu_w3t + (size_t)l * CZ * CZ, eu_b3 + l * CZ, buf_a, NE, CZ, CZ);
        ln_kernel<1><<<NE, 128, 0, stream>>>(buf_a, ef_b, eu_ln_g + l * CZ, eu_ln_b + l * CZ, ef_b);
    }

    final_out<<<NN, 128, 0, stream>>>(xs, xv, rot, mu_w, mu_b, lv_w, lv_b, (float*)d_out);
}